// Round 2
// baseline (127.672 us; speedup 1.0000x reference)
//
#include <hip/hip_runtime.h>

#define NB 4096
#define MM 128
#define NN 96
#define LL 20

typedef __attribute__((ext_vector_type(8))) short bf16x8;   // 8 bf16 (4 VGPRs)
typedef __attribute__((ext_vector_type(4)))  float f32x4;   // MFMA 16x16 acc

// ---- LDS union region ----
// Phase A: Ht_hi [rows 0..96 used, frag reads touch 0..111][72 bf16] stride 144B at off 0
//          Ht_lo same at off 18432   (row 96 = y; rows 97..111 garbage, masked on write)
// Phase A end (aliased): HTH f32 [96][100] stride 400B (col 96 = HTy)
#define HT_HI      0
#define HT_LO      18432
#define HT_STRIDE  144
#define HTH_OFF    0
#define HTH_STRIDE 400
#define U_SIZE     38400

__device__ __forceinline__ unsigned bf16_rne(float f) {
    unsigned u = __float_as_uint(f);
    return (u + 0x7fffu + ((u >> 16) & 1u)) >> 16;
}

__global__ __launch_bounds__(128, 2)
void pg_kernel(const float* __restrict__ x_ini,
               const float* __restrict__ y,
               const float* __restrict__ H,
               const float* __restrict__ xt,
               const float* __restrict__ grad_ss,
               const float* __restrict__ extra_ss,
               const float* __restrict__ gamma1,
               float* __restrict__ out)
{
    __shared__ __align__(16) char U[U_SIZE];
    __shared__ __align__(16) float yxbuf[2][NN];
    __shared__ float pgs[LL], pes[LL], pgm[LL];
    __shared__ float lsum[2];

    const int b    = blockIdx.x;
    const int tid  = threadIdx.x;
    const int lane = tid & 63;
    const int wid  = tid >> 6;

    if (tid < LL) { pgs[tid] = grad_ss[tid]; pes[tid] = extra_ss[tid]; pgm[tid] = gamma1[tid]; }

    // accumulators: wave w owns HTH row-tiles I = wid*3 .. wid*3+2, all 7 col-tiles
    f32x4 acc[3][7];
    #pragma unroll
    for (int i = 0; i < 3; ++i)
        #pragma unroll
        for (int j = 0; j < 7; ++j)
            #pragma unroll
            for (int r = 0; r < 4; ++r) acc[i][j][r] = 0.f;

    const int c32 = tid & 31;   // column within 32-group
    const int ko  = tid >> 5;   // k quarter (16 rows of H)
    const float* Hb = H + (size_t)b * (MM * NN);

    // ================= Phase A: HTH_ext = [H|y]^T [H|y] via split-bf16 MFMA =================
    for (int kh = 0; kh < 2; ++kh) {
        if (kh) __syncthreads();   // previous half's frag reads done before restaging

        // stage H columns (k-range kh*64..+63) transposed into Ht (hi/lo bf16)
        #pragma unroll
        for (int cg = 0; cg < 3; ++cg) {
            const int c = c32 + 32 * cg;
            float v[16];
            #pragma unroll
            for (int rr = 0; rr < 16; ++rr)
                v[rr] = Hb[(size_t)(kh * 64 + ko * 16 + rr) * NN + c];
            bf16x8 h0, h1, l0, l1;
            #pragma unroll
            for (int j = 0; j < 8; ++j) {
                unsigned ha = bf16_rne(v[j]);
                unsigned hb = bf16_rne(v[8 + j]);
                h0[j] = (short)ha;
                h1[j] = (short)hb;
                l0[j] = (short)bf16_rne(v[j]     - __uint_as_float(ha << 16));
                l1[j] = (short)bf16_rne(v[8 + j] - __uint_as_float(hb << 16));
            }
            char* ph = &U[HT_HI + c * HT_STRIDE + ko * 32];
            char* pl = &U[HT_LO + c * HT_STRIDE + ko * 32];
            *(bf16x8*)(ph)      = h0;
            *(bf16x8*)(ph + 16) = h1;
            *(bf16x8*)(pl)      = l0;
            *(bf16x8*)(pl + 16) = l1;
        }
        // y -> Ht row 96
        if (tid < 64) {
            float vy = y[(size_t)b * MM + kh * 64 + tid];
            unsigned hb = bf16_rne(vy);
            float lo = vy - __uint_as_float(hb << 16);
            *(unsigned short*)&U[HT_HI + 96 * HT_STRIDE + tid * 2] = (unsigned short)hb;
            *(unsigned short*)&U[HT_LO + 96 * HT_STRIDE + tid * 2] = (unsigned short)bf16_rne(lo);
        }
        __syncthreads();

        // MFMA: K=32 steps (2 per half), tiles I (3 per wave) x J (7)
        #pragma unroll
        for (int kk = 0; kk < 2; ++kk) {
            const int kb = kk * 64 + (lane >> 4) * 16;  // byte offset of this lane's 8 bf16 along k
            bf16x8 Ah[3], Al[3], Bh[7], Bl[7];
            #pragma unroll
            for (int i = 0; i < 3; ++i) {
                const int off = (wid * 48 + i * 16 + (lane & 15)) * HT_STRIDE + kb;
                Ah[i] = *(const bf16x8*)&U[HT_HI + off];
                Al[i] = *(const bf16x8*)&U[HT_LO + off];
            }
            #pragma unroll
            for (int j = 0; j < 7; ++j) {
                const int off = (j * 16 + (lane & 15)) * HT_STRIDE + kb;
                Bh[j] = *(const bf16x8*)&U[HT_HI + off];
                Bl[j] = *(const bf16x8*)&U[HT_LO + off];
            }
            #pragma unroll
            for (int i = 0; i < 3; ++i)
                #pragma unroll
                for (int j = 0; j < 7; ++j) {
                    acc[i][j] = __builtin_amdgcn_mfma_f32_16x16x32_bf16(Ah[i], Bh[j], acc[i][j], 0, 0, 0);
                    acc[i][j] = __builtin_amdgcn_mfma_f32_16x16x32_bf16(Ah[i], Bl[j], acc[i][j], 0, 0, 0);
                    acc[i][j] = __builtin_amdgcn_mfma_f32_16x16x32_bf16(Al[i], Bh[j], acc[i][j], 0, 0, 0);
                }
        }
    }
    __syncthreads();  // all frag reads done -> safe to overwrite U with HTH

    // C-write: lane holds col = lane&15, rows (lane>>4)*4 + r   [m89-verified layout]
    #pragma unroll
    for (int i = 0; i < 3; ++i)
        #pragma unroll
        for (int j = 0; j < 7; ++j) {
            const int col = j * 16 + (lane & 15);
            if (col < 97) {
                const int rowb = wid * 48 + i * 16 + (lane >> 4) * 4;
                #pragma unroll
                for (int r = 0; r < 4; ++r)
                    *(float*)&U[HTH_OFF + (rowb + r) * HTH_STRIDE + col * 4] = acc[i][j][r];
            }
        }
    __syncthreads();

    // ================= Phase B: 20 FISTA iterations, HTH row in registers =================
    float hrow[96];
    float hty = 0.f, yx_own = 0.f, x_c = 0.f;
    if (tid < NN) {
        #pragma unroll
        for (int g = 0; g < 24; ++g) {
            float4 v = *(const float4*)&U[HTH_OFF + tid * HTH_STRIDE + 16 * g];
            hrow[4*g+0] = v.x; hrow[4*g+1] = v.y; hrow[4*g+2] = v.z; hrow[4*g+3] = v.w;
        }
        hty    = *(const float*)&U[HTH_OFF + tid * HTH_STRIDE + 96 * 4];
        yx_own = x_ini[(size_t)b * NN + tid];
        x_c    = yx_own;
        yxbuf[0][tid] = yx_own;
    }
    __syncthreads();

    int cur = 0;
    for (int t = 0; t < LL; ++t) {
        if (tid < NN) {
            float w0 = 0.f, w1 = 0.f, w2 = 0.f, w3 = 0.f;
            #pragma unroll
            for (int g = 0; g < 24; ++g) {
                float4 v = *(const float4*)&yxbuf[cur][4 * g];
                w0 = fmaf(hrow[4*g+0], v.x, w0);
                w1 = fmaf(hrow[4*g+1], v.y, w1);
                w2 = fmaf(hrow[4*g+2], v.z, w2);
                w3 = fmaf(hrow[4*g+3], v.w, w3);
            }
            float w = (w0 + w1) + (w2 + w3);
            const float gs = pgs[t], es = pes[t], gm = pgm[t];
            float xb  = fmaf(-2.0f * gs, w - hty, yx_own);          // y_x - gs*2*(HTH yx - HTy)
            float cen = 2.0f * fminf(fmaxf(rintf(xb * 0.5f), -1.0f), 1.0f);
            float z   = gm * (xb - cen);
            float e   = __expf(-z);
            float ply = fmaf(2.0f, __builtin_amdgcn_rcpf(1.0f + e), -1.0f);
            float yxn = fmaf(es, ply - x_c, ply);
            x_c    = ply;
            yx_own = yxn;
            yxbuf[cur ^ 1][tid] = yxn;
        }
        cur ^= 1;
        __syncthreads();
    }

    // ---- epilogue: write x, accumulate loss ----
    float part = 0.f;
    if (tid < NN) {
        out[(size_t)b * NN + tid] = x_c;
        float d = x_c - xt[(size_t)b * NN + tid];
        part = d * d;
    }
    #pragma unroll
    for (int m = 1; m < 64; m <<= 1) part += __shfl_xor(part, m, 64);
    if ((tid & 63) == 0) lsum[tid >> 6] = part;
    __syncthreads();
    if (tid == 0) atomicAdd(out + (size_t)NB * NN, lsum[0] + lsum[1]);
}

extern "C" void kernel_launch(void* const* d_in, const int* in_sizes, int n_in,
                              void* d_out, int out_size, void* d_ws, size_t ws_size,
                              hipStream_t stream) {
    const float* x_ini    = (const float*)d_in[0];
    const float* y        = (const float*)d_in[1];
    const float* H        = (const float*)d_in[2];
    const float* xt       = (const float*)d_in[3];
    const float* grad_ss  = (const float*)d_in[4];
    const float* extra_ss = (const float*)d_in[5];
    const float* gamma1   = (const float*)d_in[6];
    float* out = (float*)d_out;

    hipMemsetAsync(out + (size_t)NB * NN, 0, sizeof(float), stream);
    pg_kernel<<<NB, 128, 0, stream>>>(x_ini, y, H, xt, grad_ss, extra_ss, gamma1, out);
}

// Round 3
// 127.487 us; speedup vs baseline: 1.0015x; 1.0015x over previous
//
#include <hip/hip_runtime.h>

#define NB 4096
#define MM 128
#define NN 96
#define LL 20

typedef __attribute__((ext_vector_type(8))) short bf16x8;   // 8 bf16 (4 VGPRs)
typedef __attribute__((ext_vector_type(4)))  float f32x4;   // MFMA 16x16 acc

// ---- LDS union region ----
// Phase A: Ht_hi [rows 0..96 used, frag reads touch 0..111][72 bf16] stride 144B at off 0
//          Ht_lo same at off 18432   (row 96 = y; rows 97..111 garbage, masked on write)
// Phase A end (aliased): HTH f32 [96][100] stride 400B (col 96 = HTy)
#define HT_HI      0
#define HT_LO      18432
#define HT_STRIDE  144
#define HTH_OFF    0
#define HTH_STRIDE 400
#define U_SIZE     38400

__device__ __forceinline__ unsigned bf16_rne(float f) {
    unsigned u = __float_as_uint(f);
    return (u + 0x7fffu + ((u >> 16) & 1u)) >> 16;
}

__global__ __launch_bounds__(128, 2)
void pg_kernel(const float* __restrict__ x_ini,
               const float* __restrict__ y,
               const float* __restrict__ H,
               const float* __restrict__ xt,
               const float* __restrict__ grad_ss,
               const float* __restrict__ extra_ss,
               const float* __restrict__ gamma1,
               float* __restrict__ out)
{
    __shared__ __align__(16) char U[U_SIZE];
    __shared__ __align__(16) float yxbuf[2][NN];
    __shared__ float pgs[LL], pes[LL], pgm[LL];
    __shared__ float lsum[2];

    const int b    = blockIdx.x;
    const int tid  = threadIdx.x;
    const int lane = tid & 63;
    const int wid  = tid >> 6;

    if (tid < LL) { pgs[tid] = grad_ss[tid]; pes[tid] = extra_ss[tid]; pgm[tid] = gamma1[tid]; }

    // accumulators: wave w owns HTH row-tiles I = wid*3 .. wid*3+2, all 7 col-tiles
    f32x4 acc[3][7];
    #pragma unroll
    for (int i = 0; i < 3; ++i)
        #pragma unroll
        for (int j = 0; j < 7; ++j)
            #pragma unroll
            for (int r = 0; r < 4; ++r) acc[i][j][r] = 0.f;

    const int c32 = tid & 31;   // column within 32-group
    const int ko  = tid >> 5;   // k quarter (16 rows of H)
    const float* Hb = H + (size_t)b * (MM * NN);

    // ================= Phase A: HTH_ext = [H|y]^T [H|y] via split-bf16 MFMA =================
    for (int kh = 0; kh < 2; ++kh) {
        if (kh) __syncthreads();   // previous half's frag reads done before restaging

        // stage H columns (k-range kh*64..+63) transposed into Ht (hi/lo bf16)
        #pragma unroll
        for (int cg = 0; cg < 3; ++cg) {
            const int c = c32 + 32 * cg;
            float v[16];
            #pragma unroll
            for (int rr = 0; rr < 16; ++rr)
                v[rr] = Hb[(size_t)(kh * 64 + ko * 16 + rr) * NN + c];
            bf16x8 h0, h1, l0, l1;
            #pragma unroll
            for (int j = 0; j < 8; ++j) {
                unsigned ha = bf16_rne(v[j]);
                unsigned hb = bf16_rne(v[8 + j]);
                h0[j] = (short)ha;
                h1[j] = (short)hb;
                l0[j] = (short)bf16_rne(v[j]     - __uint_as_float(ha << 16));
                l1[j] = (short)bf16_rne(v[8 + j] - __uint_as_float(hb << 16));
            }
            char* ph = &U[HT_HI + c * HT_STRIDE + ko * 32];
            char* pl = &U[HT_LO + c * HT_STRIDE + ko * 32];
            *(bf16x8*)(ph)      = h0;
            *(bf16x8*)(ph + 16) = h1;
            *(bf16x8*)(pl)      = l0;
            *(bf16x8*)(pl + 16) = l1;
        }
        // y -> Ht row 96
        if (tid < 64) {
            float vy = y[(size_t)b * MM + kh * 64 + tid];
            unsigned hb = bf16_rne(vy);
            float lo = vy - __uint_as_float(hb << 16);
            *(unsigned short*)&U[HT_HI + 96 * HT_STRIDE + tid * 2] = (unsigned short)hb;
            *(unsigned short*)&U[HT_LO + 96 * HT_STRIDE + tid * 2] = (unsigned short)bf16_rne(lo);
        }
        __syncthreads();

        // MFMA: K=32 steps (2 per half), tiles I (3 per wave) x J (7)
        #pragma unroll
        for (int kk = 0; kk < 2; ++kk) {
            const int kb = kk * 64 + (lane >> 4) * 16;  // byte offset of this lane's 8 bf16 along k
            bf16x8 Ah[3], Al[3], Bh[7], Bl[7];
            #pragma unroll
            for (int i = 0; i < 3; ++i) {
                const int off = (wid * 48 + i * 16 + (lane & 15)) * HT_STRIDE + kb;
                Ah[i] = *(const bf16x8*)&U[HT_HI + off];
                Al[i] = *(const bf16x8*)&U[HT_LO + off];
            }
            #pragma unroll
            for (int j = 0; j < 7; ++j) {
                const int off = (j * 16 + (lane & 15)) * HT_STRIDE + kb;
                Bh[j] = *(const bf16x8*)&U[HT_HI + off];
                Bl[j] = *(const bf16x8*)&U[HT_LO + off];
            }
            #pragma unroll
            for (int i = 0; i < 3; ++i)
                #pragma unroll
                for (int j = 0; j < 7; ++j) {
                    acc[i][j] = __builtin_amdgcn_mfma_f32_16x16x32_bf16(Ah[i], Bh[j], acc[i][j], 0, 0, 0);
                    acc[i][j] = __builtin_amdgcn_mfma_f32_16x16x32_bf16(Ah[i], Bl[j], acc[i][j], 0, 0, 0);
                    acc[i][j] = __builtin_amdgcn_mfma_f32_16x16x32_bf16(Al[i], Bh[j], acc[i][j], 0, 0, 0);
                }
        }
    }
    __syncthreads();  // all frag reads done -> safe to overwrite U with HTH

    // C-write: lane holds col = lane&15, rows (lane>>4)*4 + r   [m89-verified layout]
    #pragma unroll
    for (int i = 0; i < 3; ++i)
        #pragma unroll
        for (int j = 0; j < 7; ++j) {
            const int col = j * 16 + (lane & 15);
            if (col < 97) {
                const int rowb = wid * 48 + i * 16 + (lane >> 4) * 4;
                #pragma unroll
                for (int r = 0; r < 4; ++r)
                    *(float*)&U[HTH_OFF + (rowb + r) * HTH_STRIDE + col * 4] = acc[i][j][r];
            }
        }
    __syncthreads();

    // ================= Phase B: 20 FISTA iterations, HTH row in registers =================
    float hrow[96];
    float hty = 0.f, yx_own = 0.f, x_c = 0.f;
    if (tid < NN) {
        #pragma unroll
        for (int g = 0; g < 24; ++g) {
            float4 v = *(const float4*)&U[HTH_OFF + tid * HTH_STRIDE + 16 * g];
            hrow[4*g+0] = v.x; hrow[4*g+1] = v.y; hrow[4*g+2] = v.z; hrow[4*g+3] = v.w;
        }
        hty    = *(const float*)&U[HTH_OFF + tid * HTH_STRIDE + 96 * 4];
        yx_own = x_ini[(size_t)b * NN + tid];
        x_c    = yx_own;
        yxbuf[0][tid] = yx_own;
    }
    __syncthreads();

    int cur = 0;
    for (int t = 0; t < LL; ++t) {
        if (tid < NN) {
            float w0 = 0.f, w1 = 0.f, w2 = 0.f, w3 = 0.f;
            #pragma unroll
            for (int g = 0; g < 24; ++g) {
                float4 v = *(const float4*)&yxbuf[cur][4 * g];
                w0 = fmaf(hrow[4*g+0], v.x, w0);
                w1 = fmaf(hrow[4*g+1], v.y, w1);
                w2 = fmaf(hrow[4*g+2], v.z, w2);
                w3 = fmaf(hrow[4*g+3], v.w, w3);
            }
            float w = (w0 + w1) + (w2 + w3);
            const float gs = pgs[t], es = pes[t], gm = pgm[t];
            float xb  = fmaf(-2.0f * gs, w - hty, yx_own);          // y_x - gs*2*(HTH yx - HTy)
            float cen = 2.0f * fminf(fmaxf(rintf(xb * 0.5f), -1.0f), 1.0f);
            float z   = gm * (xb - cen);
            float e   = __expf(-z);
            float ply = fmaf(2.0f, __builtin_amdgcn_rcpf(1.0f + e), -1.0f);
            float yxn = fmaf(es, ply - x_c, ply);
            x_c    = ply;
            yx_own = yxn;
            yxbuf[cur ^ 1][tid] = yxn;
        }
        cur ^= 1;
        __syncthreads();
    }

    // ---- epilogue: write x, accumulate loss ----
    float part = 0.f;
    if (tid < NN) {
        out[(size_t)b * NN + tid] = x_c;
        float d = x_c - xt[(size_t)b * NN + tid];
        part = d * d;
    }
    #pragma unroll
    for (int m = 1; m < 64; m <<= 1) part += __shfl_xor(part, m, 64);
    if ((tid & 63) == 0) lsum[tid >> 6] = part;
    __syncthreads();
    if (tid == 0) atomicAdd(out + (size_t)NB * NN, lsum[0] + lsum[1]);
}

extern "C" void kernel_launch(void* const* d_in, const int* in_sizes, int n_in,
                              void* d_out, int out_size, void* d_ws, size_t ws_size,
                              hipStream_t stream) {
    const float* x_ini    = (const float*)d_in[0];
    const float* y        = (const float*)d_in[1];
    const float* H        = (const float*)d_in[2];
    const float* xt       = (const float*)d_in[3];
    const float* grad_ss  = (const float*)d_in[4];
    const float* extra_ss = (const float*)d_in[5];
    const float* gamma1   = (const float*)d_in[6];
    float* out = (float*)d_out;

    hipMemsetAsync(out + (size_t)NB * NN, 0, sizeof(float), stream);
    pg_kernel<<<NB, 128, 0, stream>>>(x_ini, y, H, xt, grad_ss, extra_ss, gamma1, out);
}

// Round 4
// 124.115 us; speedup vs baseline: 1.0287x; 1.0272x over previous
//
#include <hip/hip_runtime.h>

#define NB 4096
#define MM 128
#define NN 96
#define LL 20

// One block (256 threads = 4 waves) per batch.
// Thread (rg = tid>>3 in 0..31, cg = tid&7) owns H[rg*4 .. rg*4+3][cg*12 .. cg*12+11]
// in 48 registers. Per iteration:
//   u = H*yx      : 48 FMA + 3-step shfl_xor reduce over cg (low 3 lane bits)
//   u -= y
//   w = H^T*u     : 48 FMA partials, float4 scatter to LDS [32][100]
//   owners tid<96 : gather 32 rows, elementwise quantizer update, broadcast yx
__global__ __launch_bounds__(256, 2)
void pg_kernel(const float* __restrict__ x_ini,
               const float* __restrict__ y,
               const float* __restrict__ H,
               const float* __restrict__ xt,
               const float* __restrict__ grad_ss,
               const float* __restrict__ extra_ss,
               const float* __restrict__ gamma1,
               float* __restrict__ out)
{
    const int b   = blockIdx.x;
    const int tid = threadIdx.x;
    const int cg  = tid & 7;    // column group: cols cg*12 .. +11
    const int rg  = tid >> 3;   // row group:    rows rg*4  .. +3

    __shared__ __align__(16) float wp[32][100];  // row stride 400B: f4-aligned, gather 2-way (free)
    __shared__ __align__(16) float yxb[NN];
    __shared__ float pgs[LL], pes[LL], pgm[LL];
    __shared__ float lsum[4];

    if (tid < LL) { pgs[tid] = grad_ss[tid]; pes[tid] = extra_ss[tid]; pgm[tid] = gamma1[tid]; }

    // ---- own H tile -> registers (true residency: 48 floats, launch_bounds allows it) ----
    float h[4][12];
    const float* Hb = H + (size_t)b * (MM * NN) + (size_t)(rg * 4) * NN + cg * 12;
    #pragma unroll
    for (int i = 0; i < 4; ++i) {
        #pragma unroll
        for (int k = 0; k < 3; ++k) {
            float4 v = *reinterpret_cast<const float4*>(Hb + i * NN + 4 * k);
            h[i][4*k+0] = v.x; h[i][4*k+1] = v.y;
            h[i][4*k+2] = v.z; h[i][4*k+3] = v.w;
        }
    }

    // ---- own rows of y ----
    float yr[4];
    {
        float4 v = *reinterpret_cast<const float4*>(y + (size_t)b * MM + rg * 4);
        yr[0] = v.x; yr[1] = v.y; yr[2] = v.z; yr[3] = v.w;
    }

    // ---- init y_x / x for owned column ----
    float yx_own = 0.f, x_c = 0.f;
    if (tid < NN) {
        yx_own = x_ini[(size_t)b * NN + tid];
        x_c    = yx_own;
        yxb[tid] = yx_own;
    }
    __syncthreads();

    float yx[12];
    #pragma unroll
    for (int k = 0; k < 3; ++k) {
        float4 v = *reinterpret_cast<const float4*>(&yxb[cg * 12 + 4 * k]);
        yx[4*k+0]=v.x; yx[4*k+1]=v.y; yx[4*k+2]=v.z; yx[4*k+3]=v.w;
    }

    for (int t = 0; t < LL; ++t) {
        // ---- matvec1: u = H*yx partials over own 12 cols ----
        float u[4];
        #pragma unroll
        for (int i = 0; i < 4; ++i) {
            float s = 0.f;
            #pragma unroll
            for (int j = 0; j < 12; ++j) s = fmaf(h[i][j], yx[j], s);
            u[i] = s;
        }
        // reduce across 8 column groups (lane bits 0..2)
        #pragma unroll
        for (int m = 1; m <= 4; m <<= 1) {
            #pragma unroll
            for (int i = 0; i < 4; ++i) u[i] += __shfl_xor(u[i], m, 64);
        }
        #pragma unroll
        for (int i = 0; i < 4; ++i) u[i] -= yr[i];

        // ---- matvec2 partials: wp[rg][c] = sum_i h[i][c]*u[i], float4 scatter ----
        #pragma unroll
        for (int k = 0; k < 3; ++k) {
            float4 s;
            s.x = fmaf(h[0][4*k+0], u[0], fmaf(h[1][4*k+0], u[1], fmaf(h[2][4*k+0], u[2], h[3][4*k+0] * u[3])));
            s.y = fmaf(h[0][4*k+1], u[0], fmaf(h[1][4*k+1], u[1], fmaf(h[2][4*k+1], u[2], h[3][4*k+1] * u[3])));
            s.z = fmaf(h[0][4*k+2], u[0], fmaf(h[1][4*k+2], u[1], fmaf(h[2][4*k+2], u[2], h[3][4*k+2] * u[3])));
            s.w = fmaf(h[0][4*k+3], u[0], fmaf(h[1][4*k+3], u[1], fmaf(h[2][4*k+3], u[2], h[3][4*k+3] * u[3])));
            *reinterpret_cast<float4*>(&wp[rg][cg * 12 + 4 * k]) = s;
        }
        __syncthreads();

        // ---- gather + elementwise by column owners ----
        if (tid < NN) {
            float a0 = 0.f, a1 = 0.f, a2 = 0.f, a3 = 0.f;
            #pragma unroll
            for (int r = 0; r < 8; ++r) {
                a0 += wp[4*r+0][tid];
                a1 += wp[4*r+1][tid];
                a2 += wp[4*r+2][tid];
                a3 += wp[4*r+3][tid];
            }
            float w = (a0 + a1) + (a2 + a3);
            const float gs = pgs[t], es = pes[t], gm = pgm[t];
            float xb  = fmaf(-2.0f * gs, w, yx_own);                 // y_x - 2*gs*H^T(H yx - y)
            float cen = 2.0f * fminf(fmaxf(rintf(xb * 0.5f), -1.0f), 1.0f);
            float z   = gm * (xb - cen);
            float e   = __expf(-z);
            float ply = fmaf(2.0f, __builtin_amdgcn_rcpf(1.0f + e), -1.0f);
            yx_own = fmaf(es, ply - x_c, ply);
            x_c    = ply;
            if (t + 1 < LL) yxb[tid] = yx_own;
        }
        if (t + 1 < LL) {
            __syncthreads();
            #pragma unroll
            for (int k = 0; k < 3; ++k) {
                float4 v = *reinterpret_cast<const float4*>(&yxb[cg * 12 + 4 * k]);
                yx[4*k+0]=v.x; yx[4*k+1]=v.y; yx[4*k+2]=v.z; yx[4*k+3]=v.w;
            }
            __syncthreads();   // yx consumed before next iter's owner writes
        }
    }

    // ---- epilogue: write x, accumulate loss ----
    float part = 0.f;
    if (tid < NN) {
        out[(size_t)b * NN + tid] = x_c;
        float d = x_c - xt[(size_t)b * NN + tid];
        part = d * d;
    }
    #pragma unroll
    for (int m = 1; m < 64; m <<= 1) part += __shfl_xor(part, m, 64);
    if ((tid & 63) == 0) lsum[tid >> 6] = part;
    __syncthreads();
    if (tid == 0) atomicAdd(out + (size_t)NB * NN, (lsum[0] + lsum[1]) + (lsum[2] + lsum[3]));
}

extern "C" void kernel_launch(void* const* d_in, const int* in_sizes, int n_in,
                              void* d_out, int out_size, void* d_ws, size_t ws_size,
                              hipStream_t stream) {
    const float* x_ini    = (const float*)d_in[0];
    const float* y        = (const float*)d_in[1];
    const float* H        = (const float*)d_in[2];
    const float* xt       = (const float*)d_in[3];
    const float* grad_ss  = (const float*)d_in[4];
    const float* extra_ss = (const float*)d_in[5];
    const float* gamma1   = (const float*)d_in[6];
    float* out = (float*)d_out;

    hipMemsetAsync(out + (size_t)NB * NN, 0, sizeof(float), stream);
    pg_kernel<<<NB, 256, 0, stream>>>(x_ini, y, H, xt, grad_ss, extra_ss, gamma1, out);
}